// Round 11
// baseline (668.660 us; speedup 1.0000x reference)
//
#include <hip/hip_runtime.h>
#include <hip/hip_fp16.h>

#define BB 16
#define NN 1024
#define DD 256
#define NSLAB2 32       // sinkhorn slabs per batch (32 rows each), 2 batches/block
#define ETW 40          // bary: padded LDS row width (halves)

typedef _Float16 h8 __attribute__((ext_vector_type(8)));
typedef _Float16 hv4 __attribute__((ext_vector_type(4)));
typedef _Float16 h2 __attribute__((ext_vector_type(2)));
typedef float f32x4 __attribute__((ext_vector_type(4)));

#if __has_builtin(__builtin_amdgcn_exp2f)
#define EXP2F(x) __builtin_amdgcn_exp2f(x)
#else
#define EXP2F(x) exp2f(x)
#endif
#if __has_builtin(__builtin_amdgcn_logf)
#define LOG2F(x) __builtin_amdgcn_logf(x)
#else
#define LOG2F(x) log2f(x)
#endif

// log2-domain: A2s = -100*log2e*relu(1-S) - CPOS2*|i-j|   (pos prior folded in, fp16)
constexpr float K_A2  = -144.26950408889634f;                 // -100*log2(e)
constexpr float CPOS2 = (float)(0.2 * 1.4426950408889634 / 1023.0);
constexpr float C1    = 0.06931471805599453f;                 // ln2/10
constexpr float BASE2 = -10.0f;                               // log2(1/1024 + 1e-12)
constexpr float P2B   = 0x1p-10f;                             // 2^BASE2

#define PIDX(i) ((i) + ((i) >> 3))

__device__ __forceinline__ float waveReduceSum(float v) {
#pragma unroll
  for (int o = 32; o; o >>= 1) v += __shfl_xor(v, o);
  return v;
}

__device__ __forceinline__ void ldsVec16p(const float* lds, int j0, float (&out)[16]) {
#pragma unroll
  for (int k = 0; k < 8; ++k) {
    out[k] = lds[PIDX(j0 + k)];
    out[8 + k] = lds[PIDX(512 + j0 + k)];
  }
}

// ---------------- K1: normalize rows of X and Y -> fp16 ----------------
__global__ __launch_bounds__(256) void normalize_kernel(
    const float* __restrict__ X, const float* __restrict__ Y,
    _Float16* __restrict__ Xh, _Float16* __restrict__ Yh) {
  int wave = threadIdx.x >> 6;
  int lane = threadIdx.x & 63;
  int row = blockIdx.x * 4 + wave;
  const float* src;
  _Float16* dst;
  if (row < BB * NN) { src = X + (size_t)row * DD; dst = Xh + (size_t)row * DD; }
  else { int r2 = row - BB * NN; src = Y + (size_t)r2 * DD; dst = Yh + (size_t)r2 * DD; }
  float4 v = *(const float4*)(src + lane * 4);
  float ss = v.x * v.x + v.y * v.y + v.z * v.z + v.w * v.w;
  ss = waveReduceSum(ss);
  float sc = 1.0f / fmaxf(sqrtf(ss), 1e-12f);
  hv4 hv;
  hv[0] = (_Float16)(v.x * sc); hv[1] = (_Float16)(v.y * sc);
  hv[2] = (_Float16)(v.z * sc); hv[3] = (_Float16)(v.w * sc);
  *(hv4*)(dst + lane * 4) = hv;
}

// ---------------- K1b: tiled transpose X,Y -> fp16 [b][d][n] ----------------
__global__ __launch_bounds__(256) void transpose_kernel(
    const float* __restrict__ X, const float* __restrict__ Y,
    _Float16* __restrict__ XT, _Float16* __restrict__ YT) {
  __shared__ _Float16 tile[64][72];
  int zb = blockIdx.z;
  const float* E;
  _Float16* ET;
  if (zb < BB) { E = X + (size_t)zb * NN * DD; ET = XT + (size_t)zb * DD * NN; }
  else { E = Y + (size_t)(zb - BB) * NN * DD; ET = YT + (size_t)(zb - BB) * DD * NN; }
  int n0 = blockIdx.x * 64, d0 = blockIdx.y * 64;
  int t = threadIdx.x;
  int lr = t >> 2, lc = (t & 3) * 16;
#pragma unroll
  for (int k = 0; k < 16; k += 4) {
    float4 v = *(const float4*)(E + (size_t)(n0 + lr) * DD + d0 + lc + k);
    tile[lc + k + 0][lr] = (_Float16)v.x;
    tile[lc + k + 1][lr] = (_Float16)v.y;
    tile[lc + k + 2][lr] = (_Float16)v.z;
    tile[lc + k + 3][lr] = (_Float16)v.w;
  }
  __syncthreads();
#pragma unroll
  for (int k = 0; k < 16; k += 8) {
    h8 o;
#pragma unroll
    for (int j = 0; j < 8; ++j) o[j] = tile[lr][lc + k + j];
    *(h8*)(ET + (size_t)(d0 + lr) * NN + n0 + lc + k) = o;
  }
}

// ---------------- K2: both S-gemms in one dispatch (z = dir*16 + b) ----------
__global__ __launch_bounds__(256) void gemm_a2_kernel(
    const _Float16* __restrict__ Xh, const _Float16* __restrict__ Yh,
    _Float16* __restrict__ A2, _Float16* __restrict__ A2T) {
  const int zb = blockIdx.z;
  const int b = zb & 15;
  const _Float16* Ah = (zb < BB) ? Xh : Yh;
  const _Float16* Bh = (zb < BB) ? Yh : Xh;
  _Float16* Out = (zb < BB) ? A2 : A2T;
  const int I0 = blockIdx.y * 128;
  const int J0 = blockIdx.x * 128;
  const int lane = threadIdx.x & 63;
  const int wave = threadIdx.x >> 6;
  const int m = lane & 15, quad = lane >> 4;
  const _Float16* Abase = Ah + ((size_t)b * NN + I0 + wave * 32) * DD;
  const _Float16* Bbase = Bh + ((size_t)b * NN + J0) * DD;
  f32x4 acc[2][8] = {};
  for (int k0 = 0; k0 < DD; k0 += 32) {
    int koff = k0 + quad * 8;
    h8 a0 = *(const h8*)(Abase + (size_t)m * DD + koff);
    h8 a1 = *(const h8*)(Abase + (size_t)(m + 16) * DD + koff);
#pragma unroll
    for (int t = 0; t < 8; ++t) {
      h8 bf = *(const h8*)(Bbase + (size_t)(t * 16 + m) * DD + koff);
      acc[0][t] = __builtin_amdgcn_mfma_f32_16x16x32_f16(a0, bf, acc[0][t], 0, 0, 0);
      acc[1][t] = __builtin_amdgcn_mfma_f32_16x16x32_f16(a1, bf, acc[1][t], 0, 0, 0);
    }
  }
  _Float16* Ob = Out + ((size_t)b * NN + I0 + wave * 32) * NN + J0;
#pragma unroll
  for (int a = 0; a < 2; ++a)
#pragma unroll
    for (int t = 0; t < 8; ++t)
#pragma unroll
      for (int r = 0; r < 4; ++r) {
        int row = a * 16 + quad * 4 + r;
        int col = t * 16 + m;
        float s = acc[a][t][r];
        float ri = (float)(I0 + wave * 32 + row);
        float ci = (float)(J0 + col);
        Ob[(size_t)row * NN + col] =
            (_Float16)(K_A2 * fmaxf(1.0f - s, 0.0f) - CPOS2 * fabsf(ri - ci));
      }
}

// ---------------- K3: persistent sinkhorn, 2-batch interleaved --------------
// 256 blocks = (32 slabs x 32 rows, 8 batch-PAIRS), 512 threads, 1 block/CU.
// Each block holds TWO 32-row slabs from two independent batches (2p, 2p+1)
// and alternates phases: while batch b0's barrier/atomic-adds propagate
// through L3 (~1.5 us chain), the block computes b1's phase -- sequential
// in-block code guarantees the overlap (R5's co-residency failed because
// lock-step blocks wait simultaneously; independent chains interleaved in
// ONE block cannot). Exchange mechanism per batch is the proven R8 path:
// fp32 agent-scope atomic-add col sums (triple buffer), counter barrier,
// wide coherent w-read. Per-batch math identical to R8 (partials regrouped
// 16x64 -> 32x32 rows).
#define SINK_SMEM 141312

__device__ __forceinline__ void storePart2(float* p, float2 v) {
  union { float2 v; unsigned long long u; } cv;
  cv.v = v;
  __hip_atomic_store((unsigned long long*)p, cv.u, __ATOMIC_RELAXED,
                     __HIP_MEMORY_SCOPE_AGENT);
}

__device__ __forceinline__ float2 loadPart2(const float* p) {
  union { float2 v; unsigned long long u; } cv;
  cv.u = __hip_atomic_load((const unsigned long long*)p, __ATOMIC_RELAXED,
                           __HIP_MEMORY_SCOPE_AGENT);
  return cv.v;
}

__device__ __forceinline__ void atomAddF(float* p, float v) {
  (void)__hip_atomic_fetch_add(p, v, __ATOMIC_RELAXED, __HIP_MEMORY_SCOPE_AGENT);
}

// 16-B cache-bypassing (coherent) load: reads at the L3 coherence point,
// where the agent-scope atomic adds execute.
__device__ __forceinline__ float4 loadCoh4(const float* p) {
  float4 v;
  asm volatile("global_load_dwordx4 %0, %1, off sc0 sc1\n\ts_waitcnt vmcnt(0)"
               : "=v"(v)
               : "v"(p)
               : "memory");
  return v;
}

__global__ __launch_bounds__(512) void sink_persist(
    const _Float16* __restrict__ A2, float* __restrict__ Cbuf,
    float* __restrict__ Fv, float* __restrict__ Gf,
    float* __restrict__ rOut, float* __restrict__ cOut, float* __restrict__ Lrow,
    unsigned* __restrict__ bar) {
  extern __shared__ char smem[];
  _Float16* slabB = (_Float16*)smem;                     // 2 x [32][1024] fp16 K'
  float* lvB = (float*)(smem + 131072);                  // 2 x (NN + NN/8)
  float* f_lB = (float*)(smem + 140288);                 // 2 x 32 u_i
  float* m_lB = (float*)(smem + 140544);                 // 2 x 32 row max
  float* fv_lB = (float*)(smem + 140800);                // 2 x 32 final log-f
  const int slabId = blockIdx.x;                         // 0..31
  const int p = blockIdx.y;                              // 0..7 (batches 2p,2p+1)
  const int t = threadIdx.x, lane = t & 63, wave = t >> 6;
  const int j0 = lane * 8;
  const int r0w = wave * 4;                              // 4 rows per wave
  const size_t CB = (size_t)BB * NN;

  // one-time: stage both 32-row A2 slabs into LDS
#pragma unroll
  for (int sel = 0; sel < 2; ++sel) {
    const int bsel = 2 * p + sel;
    const _Float16* src = A2 + ((size_t)bsel * NN + slabId * 32) * NN;
    _Float16* slab = slabB + sel * 32 * NN;
    for (int e = t * 8; e < 32 * NN; e += 512 * 8)
      *(h8*)(slab + e) = *(const h8*)(src + e);
  }
  __syncthreads();

  // prologue: per-row max then K' = exp2(a2 - m), for both slabs
#pragma unroll
  for (int sel = 0; sel < 2; ++sel) {
    _Float16* slab = slabB + sel * 32 * NN;
    float* m_l = m_lB + sel * 32;
    h8 qa8[4], qb8[4];
#pragma unroll
    for (int r = 0; r < 4; ++r) {
      qa8[r] = *(const h8*)(slab + (size_t)(r0w + r) * NN + j0);
      qb8[r] = *(const h8*)(slab + (size_t)(r0w + r) * NN + 512 + j0);
    }
    float mr[4];
#pragma unroll
    for (int r = 0; r < 4; ++r) {
      float m = (float)qa8[r][0];
#pragma unroll
      for (int k = 1; k < 8; ++k) m = fmaxf(m, (float)qa8[r][k]);
#pragma unroll
      for (int k = 0; k < 8; ++k) m = fmaxf(m, (float)qb8[r][k]);
      mr[r] = m;
    }
#pragma unroll
    for (int o = 32; o; o >>= 1)
#pragma unroll
      for (int r = 0; r < 4; ++r) mr[r] = fmaxf(mr[r], __shfl_xor(mr[r], o));
#pragma unroll
    for (int r = 0; r < 4; ++r) {
      h8 oa, ob;
#pragma unroll
      for (int k = 0; k < 8; ++k) {
        oa[k] = (_Float16)EXP2F((float)qa8[r][k] - mr[r]);
        ob[k] = (_Float16)EXP2F((float)qb8[r][k] - mr[r]);
      }
      *(h8*)(slab + (size_t)(r0w + r) * NN + j0) = oa;
      *(h8*)(slab + (size_t)(r0w + r) * NN + 512 + j0) = ob;
      if (lane == 0) m_l[r0w + r] = mr[r];
    }
  }

  // one full sinkhorn phase for batch `sel` at iteration `it`
  auto phase = [&](int sel, int it) {
    const int bsel = 2 * p + sel;
    _Float16* slab = slabB + sel * 32 * NN;
    float* lv = lvB + sel * 1152;
    float* f_l = f_lB + sel * 32;
    float* m_l = m_lB + sel * 32;
    float* fv_l = fv_lB + sel * 32;
    unsigned* barB = bar + bsel * 16;
    if (it == 0) {
      if (t < 256) {
#pragma unroll
        for (int k = 0; k < 4; ++k) lv[PIDX(4 * t + k)] = 1.0f;
      }
    } else {
      // wait for all 32 slabs' iter-(it-1) adds (cover: other batch's phase)
      if (lane == 0) {
        unsigned target = (unsigned)NSLAB2 * (unsigned)it;
        while (__hip_atomic_load(barB, __ATOMIC_RELAXED,
                                 __HIP_MEMORY_SCOPE_AGENT) < target)
          __builtin_amdgcn_s_sleep(1);
      }
      __syncthreads();
      if (t < 256) {
        const float* Cr = Cbuf + (size_t)((it + 2) % 3) * CB + bsel * NN;
        float4 cc = loadCoh4(Cr + 4 * t);
        lv[PIDX(4 * t + 0)] = P2B / cc.x;
        lv[PIDX(4 * t + 1)] = P2B / cc.y;
        lv[PIDX(4 * t + 2)] = P2B / cc.z;
        lv[PIDX(4 * t + 3)] = P2B / cc.w;
      }
    }
    __syncthreads();
    float gv[16];
    ldsVec16p(lv, j0, gv);
    // zero my stripe of the (it+1)%3 buffer (barrier-separated from its use)
    {
      float* Cz = Cbuf + (size_t)((it + 1) % 3) * CB + bsel * NN;
      if (t < 16) storePart2(Cz + slabId * 32 + 2 * t, make_float2(0.f, 0.f));
    }
    // pass A: 4 rows per wave, s_i = sum K' * w
    float sr4[4];
#pragma unroll
    for (int r = 0; r < 4; ++r) {
      h8 qa = *(const h8*)(slab + (size_t)(r0w + r) * NN + j0);
      h8 qb = *(const h8*)(slab + (size_t)(r0w + r) * NN + 512 + j0);
      float s = 0.f;
#pragma unroll
      for (int k = 0; k < 8; ++k) s = fmaf((float)qa[k], gv[k], s);
#pragma unroll
      for (int k = 0; k < 8; ++k) s = fmaf((float)qb[k], gv[8 + k], s);
      sr4[r] = s;
    }
#pragma unroll
    for (int o = 32; o; o >>= 1)
#pragma unroll
      for (int r = 0; r < 4; ++r) sr4[r] += __shfl_xor(sr4[r], o);
    if (lane == 0) {
#pragma unroll
      for (int r = 0; r < 4; ++r) {
        f_l[r0w + r] = P2B / sr4[r];                     // u_i
        if (it == 49) {
          float flog = BASE2 - m_l[r0w + r] - LOG2F(sr4[r]);
          fv_l[r0w + r] = flog;
          Fv[bsel * NN + slabId * 32 + r0w + r] = flog;
        }
      }
    }
    __syncthreads();
    // pass B: per-thread column pair over 32 LDS rows, HW-accumulate
    float p0 = 0.f, p1 = 0.f;
    const _Float16* cp = slab + 2 * t;
#pragma unroll 4
    for (int i4 = 0; i4 < 8; ++i4) {
      float4 u4 = *(const float4*)&f_l[i4 * 4];
#pragma unroll
      for (int q = 0; q < 4; ++q) {
        h2 a = *(const h2*)(cp + (size_t)(i4 * 4 + q) * NN);
        p0 = fmaf((float)a[0], u4[q], p0);
        p1 = fmaf((float)a[1], u4[q], p1);
      }
    }
    {
      float* Ca = Cbuf + (size_t)(it % 3) * CB + bsel * NN;
      atomAddF(Ca + 2 * t, p0);
      atomAddF(Ca + 2 * t + 1, p1);
    }
    __syncthreads();                                     // drain adds + zeroes
    if (t == 0)
      (void)__hip_atomic_fetch_add(barB, 1u, __ATOMIC_RELAXED,
                                   __HIP_MEMORY_SCOPE_AGENT);
  };

  for (int it = 0; it < 50; ++it) {
    phase(0, it);   // b0's barrier latency hides under phase(1, it)
    phase(1, it);   // b1's barrier latency hides under phase(0, it+1)
  }

  // finals per batch: poll to 50 iters, compute g, marginals epilogue
#pragma unroll
  for (int sel = 0; sel < 2; ++sel) {
    const int bsel = 2 * p + sel;
    float* lv = lvB + sel * 1152;
    float* fv_l = fv_lB + sel * 32;
    unsigned* barB = bar + bsel * 16;
    if (lane == 0) {
      while (__hip_atomic_load(barB, __ATOMIC_RELAXED,
                               __HIP_MEMORY_SCOPE_AGENT) <
             (unsigned)NSLAB2 * 50u)
        __builtin_amdgcn_s_sleep(1);
    }
    __syncthreads();
    {
      const float* Cg = Cbuf + (size_t)(49 % 3) * CB + bsel * NN;
      float2 cc = loadPart2(Cg + 2 * t);
      float g0 = BASE2 - LOG2F(cc.x);
      float g1 = BASE2 - LOG2F(cc.y);
      lv[PIDX(2 * t)] = g0;
      lv[PIDX(2 * t + 1)] = g1;
      if (slabId == 0) {
        Gf[bsel * NN + 2 * t] = g0;
        Gf[bsel * NN + 2 * t + 1] = g1;
      }
    }
    __syncthreads();
    float gv[16];
    ldsVec16p(lv, j0, gv);
    // marginals: re-read original a2 from global (L2/L3-hot)
#pragma unroll
    for (int r = 0; r < 4; ++r) {
      int rl = r0w + r;
      int i = slabId * 32 + rl;
      float fi = fv_l[rl];
      const _Float16* grow = A2 + ((size_t)bsel * NN + i) * NN;
      h8 qa = *(const h8*)(grow + j0);
      h8 qb = *(const h8*)(grow + 512 + j0);
      float fr = (float)i;
      float sr = 0.f, sl = 0.f;
#pragma unroll
      for (int k = 0; k < 8; ++k) {
        float a2a = (float)qa[k];
        float a2b = (float)qb[k];
        float Ta = EXP2F(a2a + fi + gv[k]);
        float Tb = EXP2F(a2b + fi + gv[8 + k]);
        sr += Ta + Tb;
        float ca = a2a + CPOS2 * fabsf(fr - (float)(j0 + k));
        float cb = a2b + CPOS2 * fabsf(fr - (float)(512 + j0 + k));
        sl = fmaf(Ta, ca, sl);
        sl = fmaf(Tb, cb, sl);
      }
      sr = waveReduceSum(sr);
      sl = waveReduceSum(sl);
      if (lane == 0) {
        rOut[bsel * NN + i] = sr;
        cOut[bsel * NN + i] = EXP2F(BASE2);
        Lrow[bsel * NN + i] = -C1 * sl;
      }
    }
    __syncthreads();
  }
}

// ---------------- K6: MFMA bary, LDS-staged ET ------------------------------
// 512 blocks of 64 rows x FULL D. ET k-tile (256x32, 16 KB) staged to LDS
// double-buffered with coalesced loads; B-operands via ds_read_b128 at 80-B
// row stride (2-way bank = free). A2-fragment prefetch one step ahead.
__global__ __launch_bounds__(256) void bary_mfma_kernel(
    const _Float16* __restrict__ A2, const _Float16* __restrict__ A2T,
    const float* __restrict__ F, const float* __restrict__ G,
    const float* __restrict__ r, const float* __restrict__ c,
    const _Float16* __restrict__ XT, const _Float16* __restrict__ YT,
    const float* __restrict__ X, const float* __restrict__ Y,
    float* __restrict__ baryA, float* __restrict__ baryB) {
  __shared__ float gl[NN];
  __shared__ float red[4];
  __shared__ _Float16 etile[2][256 * ETW];   // 2 x 20 KB
  int id = blockIdx.x + blockIdx.y * gridDim.x + blockIdx.z * gridDim.x * gridDim.y;
  int w = (id >> 3) + (id & 7) * 64;   // 0..511, contiguous per XCD
  const int I0 = (w & 15) * 64;
  const int bz = w >> 4;               // 0..31
  const int b = bz & 15;
  const int z = bz >> 4;
  const _Float16* P = z ? A2T : A2;
  const float* rowv = z ? G : F;
  const float* colv = z ? F : G;
  const float* denom = z ? c : r;
  const _Float16* EmbT = z ? XT : YT;
  const float* Ref = z ? Y : X;
  float* baryAcc = z ? baryB : baryA;
  const int t = threadIdx.x, lane = t & 63, wave = t >> 6;
  const int m = lane & 15, quad = lane >> 4;
  gl[t] = colv[b * NN + t];
  gl[t + 256] = colv[b * NN + t + 256];
  gl[t + 512] = colv[b * NN + t + 512];
  gl[t + 768] = colv[b * NN + t + 768];
  const int row = I0 + wave * 16 + m;
  const float fi = rowv[b * NN + row] + 10.0f;        // fold 2^10 scale
  const _Float16* Pr = P + (size_t)b * NN * NN + (size_t)row * NN + quad * 8;
  const _Float16* ET = EmbT + (size_t)b * DD * NN;

  auto stageET = [&](int buf, int kc) {
#pragma unroll
    for (int i = 0; i < 4; ++i) {
      int rr = (t >> 2) + i * 64;
      int ch = t & 3;
      h8 v = *(const h8*)(ET + (size_t)rr * NN + kc + ch * 8);
      *(h8*)(&etile[buf][rr * ETW + ch * 8]) = v;
    }
  };

  f32x4 acc[16];
#pragma unroll
  for (int i = 0; i < 16; ++i) acc[i] = (f32x4){0.f, 0.f, 0.f, 0.f};
  stageET(0, 0);
  h8 a2v = *(const h8*)(Pr);                          // prime A2 pipeline
  __syncthreads();                                    // covers gl + etile[0]
  int buf = 0;
  for (int kc = 0; kc < NN; kc += 32) {
    const int kn = kc + 32;
    if (kn < NN) stageET(buf ^ 1, kn);                // prefetch next tile
    h8 a2n = a2v;
    if (kn < NN) a2n = *(const h8*)(Pr + kn);         // prefetch next a2
    float4 g0 = *(const float4*)&gl[kc + quad * 8];
    float4 g1 = *(const float4*)&gl[kc + quad * 8 + 4];
    h8 af;
    af[0] = (_Float16)EXP2F((float)a2v[0] + fi + g0.x);
    af[1] = (_Float16)EXP2F((float)a2v[1] + fi + g0.y);
    af[2] = (_Float16)EXP2F((float)a2v[2] + fi + g0.z);
    af[3] = (_Float16)EXP2F((float)a2v[3] + fi + g0.w);
    af[4] = (_Float16)EXP2F((float)a2v[4] + fi + g1.x);
    af[5] = (_Float16)EXP2F((float)a2v[5] + fi + g1.y);
    af[6] = (_Float16)EXP2F((float)a2v[6] + fi + g1.z);
    af[7] = (_Float16)EXP2F((float)a2v[7] + fi + g1.w);
#pragma unroll
    for (int nt = 0; nt < 16; ++nt) {
      h8 bf = *(const h8*)(&etile[buf][(nt * 16 + m) * ETW + quad * 8]);
      acc[nt] = __builtin_amdgcn_mfma_f32_16x16x32_f16(af, bf, acc[nt], 0, 0, 0);
    }
    a2v = a2n;
    __syncthreads();                                  // etile[buf^1] ready
    buf ^= 1;
  }
  float vs = 0.f;
#pragma unroll
  for (int r4 = 0; r4 < 4; ++r4) {
    int iabs = I0 + wave * 16 + quad * 4 + r4;
    float inv = 1.0f / (1024.0f * (denom[b * NN + iabs] + 1e-8f));
    const float* Rrow = Ref + ((size_t)b * NN + iabs) * DD;
#pragma unroll
    for (int nt = 0; nt < 16; ++nt) {
      int d = nt * 16 + m;
      float val = Rrow[d] - acc[nt][r4] * inv;
      vs = fmaf(val, val, vs);
    }
  }
  vs = waveReduceSum(vs);
  if (lane == 0) red[wave] = vs;
  __syncthreads();
  if (t == 0) atomicAdd(baryAcc + b, red[0] + red[1] + red[2] + red[3]);
}

// ---------------- K7: partial global sums X*r, Y*c ----------------
__global__ __launch_bounds__(256) void xg_kernel(
    const float* __restrict__ X, const float* __restrict__ Y,
    const float* __restrict__ r, const float* __restrict__ c,
    float* __restrict__ xgp, float* __restrict__ ygp) {
  const int b = blockIdx.y, seg = blockIdx.x, d = threadIdx.x;
  float ax = 0.f, ay = 0.f;
  for (int ii = 0; ii < 256; ++ii) {
    int i = seg * 256 + ii;
    float rvv = r[b * NN + i];
    float cvv = c[b * NN + i];
    ax = fmaf(X[((size_t)b * NN + i) * DD + d], rvv, ax);
    ay = fmaf(Y[((size_t)b * NN + i) * DD + d], cvv, ay);
  }
  xgp[(size_t)(b * 4 + seg) * DD + d] = ax;
  ygp[(size_t)(b * 4 + seg) * DD + d] = ay;
}

// ---------------- K8: per-batch finalize ----------------
__global__ __launch_bounds__(256) void finalize_batch(
    const float* __restrict__ r, const float* __restrict__ c,
    const float* __restrict__ Lrow, const float* __restrict__ xgp,
    const float* __restrict__ ygp, const float* __restrict__ baryA,
    const float* __restrict__ baryB, float* __restrict__ lossArr) {
  const int b = blockIdx.x;
  const int t = threadIdx.x;
  __shared__ float sd[256];
  auto bsum = [&](float v) -> float {
    sd[t] = v; __syncthreads();
    for (int o = 128; o; o >>= 1) { if (t < o) sd[t] += sd[t + o]; __syncthreads(); }
    float res = sd[0]; __syncthreads();
    return res;
  };
  float vr = 0.f, vc = 0.f, vl = 0.f;
  for (int k = 0; k < 4; ++k) {
    int i = t + 256 * k;
    vr += r[b * NN + i];
    vc += c[b * NN + i];
    vl += Lrow[b * NN + i];
  }
  float sumR = bsum(vr);
  float sumC = bsum(vc);
  float Lmain = bsum(vl);
  float xg = (xgp[(size_t)(b * 4 + 0) * DD + t] + xgp[(size_t)(b * 4 + 1) * DD + t] +
              xgp[(size_t)(b * 4 + 2) * DD + t] + xgp[(size_t)(b * 4 + 3) * DD + t]) /
             (sumR + 1e-8f);
  float yg = (ygp[(size_t)(b * 4 + 0) * DD + t] + ygp[(size_t)(b * 4 + 1) * DD + t] +
              ygp[(size_t)(b * 4 + 2) * DD + t] + ygp[(size_t)(b * 4 + 3) * DD + t]) /
             (sumC + 1e-8f);
  float nx = bsum(xg * xg);
  float ny = bsum(yg * yg);
  float dt = bsum(xg * yg);
  if (t == 0) {
    float mx = fmaxf(sqrtf(nx), 1e-12f);
    float my = fmaxf(sqrtf(ny), 1e-12f);
    float cosv = dt / (mx * my);
    float lb = (baryA[b] + baryB[b]) * (1.0f / ((float)NN * (float)DD));
    lossArr[b] = Lmain + 0.5f * lb + 0.2f * (1.0f - cosv);
  }
}

__global__ void final_mean(const float* __restrict__ lossArr, float* __restrict__ out) {
  int t = threadIdx.x;
  float v = (t < BB) ? lossArr[t] : 0.f;
  v = waveReduceSum(v);
  if (t == 0) out[0] = v * (1.0f / BB);
}

// ---------------- launch ----------------
extern "C" void kernel_launch(void* const* d_in, const int* in_sizes, int n_in,
                              void* d_out, int out_size, void* d_ws, size_t ws_size,
                              hipStream_t stream) {
  const float* X = (const float*)d_in[0];
  const float* Y = (const float*)d_in[1];
  float* out = (float*)d_out;
  char* ws = (char*)d_ws;
  size_t off = 0;
  auto take = [&](size_t bytes) -> char* {
    char* p = ws + off;
    off = (off + bytes + 255) & ~(size_t)255;
    return p;
  };
  _Float16* Xh = (_Float16*)take((size_t)BB * NN * DD * 2);
  _Float16* Yh = (_Float16*)take((size_t)BB * NN * DD * 2);
  _Float16* XT_h = (_Float16*)take((size_t)BB * DD * NN * 2);
  _Float16* YT_h = (_Float16*)take((size_t)BB * DD * NN * 2);
  _Float16* A2 = (_Float16*)take((size_t)BB * NN * NN * 2);
  _Float16* A2T = (_Float16*)take((size_t)BB * NN * NN * 2);
  size_t zstart = off;
  float* Cbuf = (float*)take((size_t)3 * BB * NN * 4);   // triple-buffer col sums
  float* baryA = (float*)take(64);
  float* baryB = (float*)take(64);
  unsigned* bar = (unsigned*)take((size_t)BB * 16 * 4);  // per-batch barrier counters
  size_t zlen = off - zstart;
  float* Fv = (float*)take((size_t)BB * NN * 4);
  float* Gf = (float*)take((size_t)BB * NN * 4);
  float* r = (float*)take((size_t)BB * NN * 4);
  float* c = (float*)take((size_t)BB * NN * 4);
  float* Lrow = (float*)take((size_t)BB * NN * 4);
  float* xgp = (float*)take((size_t)BB * 4 * DD * 4);
  float* ygp = (float*)take((size_t)BB * 4 * DD * 4);
  float* lossArr = (float*)take(64);
  (void)in_sizes; (void)n_in; (void)out_size; (void)ws_size;

  (void)hipMemsetAsync(ws + zstart, 0, zlen, stream);

  normalize_kernel<<<dim3(2 * BB * NN / 4), dim3(256), 0, stream>>>(X, Y, Xh, Yh);
  transpose_kernel<<<dim3(NN / 64, DD / 64, 2 * BB), dim3(256), 0, stream>>>(X, Y, XT_h,
                                                                             YT_h);
  gemm_a2_kernel<<<dim3(NN / 128, NN / 128, 2 * BB), dim3(256), 0, stream>>>(Xh, Yh, A2,
                                                                             A2T);
  // persistent sinkhorn (50 iters + final g + marginals fused), 2-batch/block
  (void)hipFuncSetAttribute(reinterpret_cast<const void*>(sink_persist),
                            hipFuncAttributeMaxDynamicSharedMemorySize, SINK_SMEM);
  {
    void* args[] = {(void*)&A2, (void*)&Cbuf, (void*)&Fv, (void*)&Gf,
                    (void*)&r,  (void*)&c,    (void*)&Lrow, (void*)&bar};
    hipError_t lerr = hipLaunchCooperativeKernel(
        reinterpret_cast<void*>(sink_persist), dim3(NSLAB2, BB / 2), dim3(512), args,
        SINK_SMEM, stream);
    if (lerr != hipSuccess) {
      // 256 blocks at 1/CU trivially co-resident; plain launch equivalent.
      sink_persist<<<dim3(NSLAB2, BB / 2), dim3(512), SINK_SMEM, stream>>>(
          A2, Cbuf, Fv, Gf, r, c, Lrow, bar);
    }
  }
  bary_mfma_kernel<<<dim3(NN / 64, BB, 2), dim3(256), 0, stream>>>(
      A2, A2T, Fv, Gf, r, c, XT_h, YT_h, X, Y, baryA, baryB);
  xg_kernel<<<dim3(4, BB), dim3(256), 0, stream>>>(X, Y, r, c, xgp, ygp);
  finalize_batch<<<dim3(BB), dim3(256), 0, stream>>>(r, c, Lrow, xgp, ygp, baryA, baryB,
                                                     lossArr);
  final_mean<<<dim3(1), dim3(64), 0, stream>>>(lossArr, out);
}

// Round 12
// 494.127 us; speedup vs baseline: 1.3532x; 1.3532x over previous
//
#include <hip/hip_runtime.h>
#include <hip/hip_fp16.h>

#define BB 16
#define NN 1024
#define DD 256
#define NSLAB 16        // sinkhorn slabs per batch (64 rows each)
#define ETW 40          // bary: padded LDS row width (halves)

typedef _Float16 h8 __attribute__((ext_vector_type(8)));
typedef _Float16 hv4 __attribute__((ext_vector_type(4)));
typedef _Float16 h2 __attribute__((ext_vector_type(2)));
typedef float f32x4 __attribute__((ext_vector_type(4)));

#if __has_builtin(__builtin_amdgcn_exp2f)
#define EXP2F(x) __builtin_amdgcn_exp2f(x)
#else
#define EXP2F(x) exp2f(x)
#endif
#if __has_builtin(__builtin_amdgcn_logf)
#define LOG2F(x) __builtin_amdgcn_logf(x)
#else
#define LOG2F(x) log2f(x)
#endif

// log2-domain: A2s = -100*log2e*relu(1-S) - CPOS2*|i-j|   (pos prior folded in, fp16)
constexpr float K_A2  = -144.26950408889634f;                 // -100*log2(e)
constexpr float CPOS2 = (float)(0.2 * 1.4426950408889634 / 1023.0);
constexpr float C1    = 0.06931471805599453f;                 // ln2/10
constexpr float BASE2 = -10.0f;                               // log2(1/1024 + 1e-12)
constexpr float P2B   = 0x1p-10f;                             // 2^BASE2

#define PIDX(i) ((i) + ((i) >> 3))

__device__ __forceinline__ float waveReduceSum(float v) {
#pragma unroll
  for (int o = 32; o; o >>= 1) v += __shfl_xor(v, o);
  return v;
}

__device__ __forceinline__ void ldsVec16p(const float* lds, int j0, float (&out)[16]) {
#pragma unroll
  for (int k = 0; k < 8; ++k) {
    out[k] = lds[PIDX(j0 + k)];
    out[8 + k] = lds[PIDX(512 + j0 + k)];
  }
}

// ---------------- K1: normalize rows of X and Y -> fp16 ----------------
__global__ __launch_bounds__(256) void normalize_kernel(
    const float* __restrict__ X, const float* __restrict__ Y,
    _Float16* __restrict__ Xh, _Float16* __restrict__ Yh) {
  int wave = threadIdx.x >> 6;
  int lane = threadIdx.x & 63;
  int row = blockIdx.x * 4 + wave;
  const float* src;
  _Float16* dst;
  if (row < BB * NN) { src = X + (size_t)row * DD; dst = Xh + (size_t)row * DD; }
  else { int r2 = row - BB * NN; src = Y + (size_t)r2 * DD; dst = Yh + (size_t)r2 * DD; }
  float4 v = *(const float4*)(src + lane * 4);
  float ss = v.x * v.x + v.y * v.y + v.z * v.z + v.w * v.w;
  ss = waveReduceSum(ss);
  float sc = 1.0f / fmaxf(sqrtf(ss), 1e-12f);
  hv4 hv;
  hv[0] = (_Float16)(v.x * sc); hv[1] = (_Float16)(v.y * sc);
  hv[2] = (_Float16)(v.z * sc); hv[3] = (_Float16)(v.w * sc);
  *(hv4*)(dst + lane * 4) = hv;
}

// ---------------- K1b: tiled transpose X,Y -> fp16 [b][d][n] ----------------
__global__ __launch_bounds__(256) void transpose_kernel(
    const float* __restrict__ X, const float* __restrict__ Y,
    _Float16* __restrict__ XT, _Float16* __restrict__ YT) {
  __shared__ _Float16 tile[64][72];
  int zb = blockIdx.z;
  const float* E;
  _Float16* ET;
  if (zb < BB) { E = X + (size_t)zb * NN * DD; ET = XT + (size_t)zb * DD * NN; }
  else { E = Y + (size_t)(zb - BB) * NN * DD; ET = YT + (size_t)(zb - BB) * DD * NN; }
  int n0 = blockIdx.x * 64, d0 = blockIdx.y * 64;
  int t = threadIdx.x;
  int lr = t >> 2, lc = (t & 3) * 16;
#pragma unroll
  for (int k = 0; k < 16; k += 4) {
    float4 v = *(const float4*)(E + (size_t)(n0 + lr) * DD + d0 + lc + k);
    tile[lc + k + 0][lr] = (_Float16)v.x;
    tile[lc + k + 1][lr] = (_Float16)v.y;
    tile[lc + k + 2][lr] = (_Float16)v.z;
    tile[lc + k + 3][lr] = (_Float16)v.w;
  }
  __syncthreads();
#pragma unroll
  for (int k = 0; k < 16; k += 8) {
    h8 o;
#pragma unroll
    for (int j = 0; j < 8; ++j) o[j] = tile[lr][lc + k + j];
    *(h8*)(ET + (size_t)(d0 + lr) * NN + n0 + lc + k) = o;
  }
}

// ---------------- K2: ONE S-gemm per (b, tile), dual-write A2 + A2T ---------
// A2T is bitwise transpose(A2): the reverse-direction GEMM computes the same
// products in the same k-order, so the old z>=16 GEMM half was redundant.
// The 128x128 output tile is staged in LDS and written twice, both coalesced
// (the old scalar stores were 512-B-strided fragments). Grid z: 32 -> 16.
__global__ __launch_bounds__(256) void gemm_a2_kernel(
    const _Float16* __restrict__ Xh, const _Float16* __restrict__ Yh,
    _Float16* __restrict__ A2, _Float16* __restrict__ A2T) {
  __shared__ _Float16 tile[128][136];
  const int b = blockIdx.z;
  const int I0 = blockIdx.y * 128;
  const int J0 = blockIdx.x * 128;
  const int lane = threadIdx.x & 63;
  const int wave = threadIdx.x >> 6;
  const int m = lane & 15, quad = lane >> 4;
  const _Float16* Abase = Xh + ((size_t)b * NN + I0 + wave * 32) * DD;
  const _Float16* Bbase = Yh + ((size_t)b * NN + J0) * DD;
  f32x4 acc[2][8] = {};
  for (int k0 = 0; k0 < DD; k0 += 32) {
    int koff = k0 + quad * 8;
    h8 a0 = *(const h8*)(Abase + (size_t)m * DD + koff);
    h8 a1 = *(const h8*)(Abase + (size_t)(m + 16) * DD + koff);
#pragma unroll
    for (int t = 0; t < 8; ++t) {
      h8 bf = *(const h8*)(Bbase + (size_t)(t * 16 + m) * DD + koff);
      acc[0][t] = __builtin_amdgcn_mfma_f32_16x16x32_f16(a0, bf, acc[0][t], 0, 0, 0);
      acc[1][t] = __builtin_amdgcn_mfma_f32_16x16x32_f16(a1, bf, acc[1][t], 0, 0, 0);
    }
  }
#pragma unroll
  for (int a = 0; a < 2; ++a)
#pragma unroll
    for (int t = 0; t < 8; ++t)
#pragma unroll
      for (int r = 0; r < 4; ++r) {
        int row = wave * 32 + a * 16 + quad * 4 + r;   // 0..127
        int col = t * 16 + m;                          // 0..127
        float s = acc[a][t][r];
        float ri = (float)(I0 + row);
        float ci = (float)(J0 + col);
        tile[row][col] =
            (_Float16)(K_A2 * fmaxf(1.0f - s, 0.0f) - CPOS2 * fabsf(ri - ci));
      }
  __syncthreads();
  const int t = threadIdx.x;
  // A2 write: row rr = t>>1, chunks (t&1)*8 + i (16 x 8 halves = 128 cols)
  {
    int rr = t >> 1;
    _Float16* Orow = A2 + ((size_t)b * NN + I0 + rr) * NN + J0;
#pragma unroll
    for (int i = 0; i < 8; ++i) {
      int cc = ((t & 1) * 8 + i) * 8;
      h8 o;
#pragma unroll
      for (int j = 0; j < 8; ++j) o[j] = tile[rr][cc + j];
      *(h8*)(Orow + cc) = o;
    }
  }
  // A2T write: A2T[J0+cr][I0+cc] = tile[cc][cr]
  {
    int ch = t & 15;                                  // cc chunk: cc = ch*8+j
    int crb = t >> 4;                                 // 0..15
#pragma unroll
    for (int i = 0; i < 8; ++i) {
      int cr = crb + i * 16;                          // 0..127
      h8 o;
#pragma unroll
      for (int j = 0; j < 8; ++j) o[j] = tile[ch * 8 + j][cr];
      *(h8*)(A2T + ((size_t)b * NN + J0 + cr) * NN + I0 + ch * 8) = o;
    }
  }
}

// ---------------- K3: persistent sinkhorn, LINEAR domain (R8/R10 proven) ----
// 256 blocks = (16 slabs x 64 rows, 16 batches), 512 threads, 1 block/CU.
// PLAIN launch (cooperative launch overhead suspected ~100 us; 256 blocks at
// 1 block/CU are trivially co-resident, which is all the barrier needs).
#define SINK_SMEM (131072 + 4608 + 256 + 256 + 256 + 256)

__device__ __forceinline__ void storePart2(float* p, float2 v) {
  union { float2 v; unsigned long long u; } cv;
  cv.v = v;
  __hip_atomic_store((unsigned long long*)p, cv.u, __ATOMIC_RELAXED,
                     __HIP_MEMORY_SCOPE_AGENT);
}

__device__ __forceinline__ float2 loadPart2(const float* p) {
  union { float2 v; unsigned long long u; } cv;
  cv.u = __hip_atomic_load((const unsigned long long*)p, __ATOMIC_RELAXED,
                           __HIP_MEMORY_SCOPE_AGENT);
  return cv.v;
}

__device__ __forceinline__ void atomAddF(float* p, float v) {
  (void)__hip_atomic_fetch_add(p, v, __ATOMIC_RELAXED, __HIP_MEMORY_SCOPE_AGENT);
}

// 16-B cache-bypassing (coherent) load: reads at the L3 coherence point,
// where the agent-scope atomic adds execute.
__device__ __forceinline__ float4 loadCoh4(const float* p) {
  float4 v;
  asm volatile("global_load_dwordx4 %0, %1, off sc0 sc1\n\ts_waitcnt vmcnt(0)"
               : "=v"(v)
               : "v"(p)
               : "memory");
  return v;
}

__global__ __launch_bounds__(512) void sink_persist(
    const _Float16* __restrict__ A2, float* __restrict__ Cbuf,
    float* __restrict__ Fv, float* __restrict__ Gf,
    float* __restrict__ rOut, float* __restrict__ cOut, float* __restrict__ Lrow,
    unsigned* __restrict__ bar) {
  extern __shared__ char smem[];
  _Float16* slab = (_Float16*)smem;                      // [64][1024] fp16 K'
  float* lv = (float*)(smem + 131072);                   // padded w, NN + NN/8
  float* f_l = (float*)(smem + 135680);                  // [64] u_i
  float* m_l = (float*)(smem + 135936);                  // [64] row max of a2
  float* fv_l = (float*)(smem + 136192);                 // [64] final log-f
  volatile unsigned* dflag = (volatile unsigned*)(smem + 136448);
  const int b = blockIdx.y;
  const int slabId = blockIdx.x;                         // 0..15
  const int t = threadIdx.x, lane = t & 63, wave = t >> 6;
  unsigned* barB = bar + b * 16;                         // 64 B padded counters

  // one-time: stage this block's 64-row A2 slab into LDS
  const _Float16* src = A2 + ((size_t)b * NN + slabId * 64) * NN;
  for (int e = t * 8; e < 64 * NN; e += 512 * 8)
    *(h8*)(slab + e) = *(const h8*)(src + e);
  __syncthreads();

  const int j0 = lane * 8;
  const int r0w = wave * 8;                              // 8 rows per wave

  // prologue: per-row max (batched shuffle reduce), then K' = exp2(a2 - m)
  {
    h8 qa8[8], qb8[8];
#pragma unroll
    for (int r = 0; r < 8; ++r) {
      qa8[r] = *(const h8*)(slab + (size_t)(r0w + r) * NN + j0);
      qb8[r] = *(const h8*)(slab + (size_t)(r0w + r) * NN + 512 + j0);
    }
    float mr[8];
#pragma unroll
    for (int r = 0; r < 8; ++r) {
      float m = (float)qa8[r][0];
#pragma unroll
      for (int k = 1; k < 8; ++k) m = fmaxf(m, (float)qa8[r][k]);
#pragma unroll
      for (int k = 0; k < 8; ++k) m = fmaxf(m, (float)qb8[r][k]);
      mr[r] = m;
    }
#pragma unroll
    for (int o = 32; o; o >>= 1)
#pragma unroll
      for (int r = 0; r < 8; ++r) mr[r] = fmaxf(mr[r], __shfl_xor(mr[r], o));
#pragma unroll
    for (int r = 0; r < 8; ++r) {
      h8 oa, ob;
#pragma unroll
      for (int k = 0; k < 8; ++k) {
        oa[k] = (_Float16)EXP2F((float)qa8[r][k] - mr[r]);
        ob[k] = (_Float16)EXP2F((float)qb8[r][k] - mr[r]);
      }
      *(h8*)(slab + (size_t)(r0w + r) * NN + j0) = oa;
      *(h8*)(slab + (size_t)(r0w + r) * NN + 512 + j0) = ob;
      if (lane == 0) m_l[r0w + r] = mr[r];
    }
  }

  const size_t CB = (size_t)BB * NN;
  float gv[16];

  for (int it = 0; it < 50; ++it) {
    // prologue: w from previous iteration's accumulated col sums
    if (it == 0) {
      lv[PIDX(2 * t)] = 1.0f;
      lv[PIDX(2 * t + 1)] = 1.0f;
    } else if (t < 256) {
      const float* Cr = Cbuf + (size_t)((it + 2) % 3) * CB + b * NN;  // (it-1)%3
      float4 cc = loadCoh4(Cr + 4 * t);
      lv[PIDX(4 * t + 0)] = P2B / cc.x;
      lv[PIDX(4 * t + 1)] = P2B / cc.y;
      lv[PIDX(4 * t + 2)] = P2B / cc.z;
      lv[PIDX(4 * t + 3)] = P2B / cc.w;
    }
    if (t == 0) *dflag = 0;
    __syncthreads();
    ldsVec16p(lv, j0, gv);
    // zero my stripe of the (it+1)%3 buffer (read at it+2; adds at it+1 --
    // all barrier-separated). Issued early to drain under pass A.
    {
      float* Cz = Cbuf + (size_t)((it + 1) % 3) * CB + b * NN;
      if (t < 32) storePart2(Cz + slabId * 64 + 2 * t, make_float2(0.f, 0.f));
    }
    // pass A: 8 rows per wave, s_i = sum K' * w (pure FMA, batched reduce)
    float sr8[8];
#pragma unroll
    for (int r = 0; r < 8; ++r) {
      h8 qa = *(const h8*)(slab + (size_t)(r0w + r) * NN + j0);
      h8 qb = *(const h8*)(slab + (size_t)(r0w + r) * NN + 512 + j0);
      float s = 0.f;
#pragma unroll
      for (int k = 0; k < 8; ++k) s = fmaf((float)qa[k], gv[k], s);
#pragma unroll
      for (int k = 0; k < 8; ++k) s = fmaf((float)qb[k], gv[8 + k], s);
      sr8[r] = s;
    }
#pragma unroll
    for (int o = 32; o; o >>= 1)
#pragma unroll
      for (int r = 0; r < 8; ++r) sr8[r] += __shfl_xor(sr8[r], o);
    if (lane == 0) {
#pragma unroll
      for (int r = 0; r < 8; ++r) {
        f_l[r0w + r] = P2B / sr8[r];                     // u_i
        if (it == 49) {
          float flog = BASE2 - m_l[r0w + r] - LOG2F(sr8[r]);
          fv_l[r0w + r] = flog;
          Fv[b * NN + slabId * 64 + r0w + r] = flog;
        }
      }
    }
    __syncthreads();
    // pass B: per-thread column pair over 64 LDS rows, then HW-accumulate
    float p0 = 0.f, p1 = 0.f;
    const _Float16* cp = slab + 2 * t;
#pragma unroll 4
    for (int i4 = 0; i4 < 16; ++i4) {
      float4 u4 = *(const float4*)&f_l[i4 * 4];
#pragma unroll
      for (int q = 0; q < 4; ++q) {
        h2 a = *(const h2*)(cp + (size_t)(i4 * 4 + q) * NN);
        p0 = fmaf((float)a[0], u4[q], p0);
        p1 = fmaf((float)a[1], u4[q], p1);
      }
    }
    {
      float* Ca = Cbuf + (size_t)(it % 3) * CB + b * NN;
      atomAddF(Ca + 2 * t, p0);
      atomAddF(Ca + 2 * t + 1, p1);
    }
    // per-batch 16-block barrier: __syncthreads drains vmcnt(0) (orders the
    // adds + zeroes before the counter bump). 8 de-phased pollers + LDS flag.
    __syncthreads();
    if (t == 0)
      __hip_atomic_fetch_add(barB, 1u, __ATOMIC_RELAXED, __HIP_MEMORY_SCOPE_AGENT);
    if (lane == 0) {
      unsigned target = (unsigned)NSLAB * (unsigned)(it + 1);
      while (*dflag == 0) {
        unsigned v = __hip_atomic_load(barB, __ATOMIC_RELAXED,
                                       __HIP_MEMORY_SCOPE_AGENT);
        if (v >= target) { *dflag = 1; break; }
        __builtin_amdgcn_s_sleep(1);
      }
    }
    __syncthreads();
  }

  // final g (50th g-update) -> lv (log domain); slab 0 publishes Gf for bary
  {
    const float* Cg = Cbuf + (size_t)(49 % 3) * CB + b * NN;
    float2 cc = loadPart2(Cg + 2 * t);
    float g0 = BASE2 - LOG2F(cc.x);
    float g1 = BASE2 - LOG2F(cc.y);
    lv[PIDX(2 * t)] = g0;
    lv[PIDX(2 * t + 1)] = g1;
    if (slabId == 0) {
      Gf[b * NN + 2 * t] = g0;
      Gf[b * NN + 2 * t + 1] = g1;
    }
  }
  __syncthreads();
  ldsVec16p(lv, j0, gv);

  // fused marginals epilogue: re-read original a2 from global (L2/L3-hot).
#pragma unroll
  for (int r = 0; r < 8; ++r) {
    int rl = r0w + r;
    int i = slabId * 64 + rl;
    float fi = fv_l[rl];
    const _Float16* grow = A2 + ((size_t)b * NN + i) * NN;
    h8 qa = *(const h8*)(grow + j0);
    h8 qb = *(const h8*)(grow + 512 + j0);
    float fr = (float)i;
    float sr = 0.f, sl = 0.f;
#pragma unroll
    for (int k = 0; k < 8; ++k) {
      float a2a = (float)qa[k];
      float a2b = (float)qb[k];
      float Ta = EXP2F(a2a + fi + gv[k]);
      float Tb = EXP2F(a2b + fi + gv[8 + k]);
      sr += Ta + Tb;
      float ca = a2a + CPOS2 * fabsf(fr - (float)(j0 + k));
      float cb = a2b + CPOS2 * fabsf(fr - (float)(512 + j0 + k));
      sl = fmaf(Ta, ca, sl);
      sl = fmaf(Tb, cb, sl);
    }
    sr = waveReduceSum(sr);
    sl = waveReduceSum(sl);
    if (lane == 0) {
      rOut[b * NN + i] = sr;
      cOut[b * NN + i] = EXP2F(BASE2);
      Lrow[b * NN + i] = -C1 * sl;
    }
  }
}

// ---------------- K6: MFMA bary, LDS-staged ET ------------------------------
// 512 blocks of 64 rows x FULL D. ET k-tile (256x32, 16 KB) staged to LDS
// double-buffered with coalesced loads; B-operands via ds_read_b128 at 80-B
// row stride (2-way bank = free). A2-fragment prefetch one step ahead.
__global__ __launch_bounds__(256) void bary_mfma_kernel(
    const _Float16* __restrict__ A2, const _Float16* __restrict__ A2T,
    const float* __restrict__ F, const float* __restrict__ G,
    const float* __restrict__ r, const float* __restrict__ c,
    const _Float16* __restrict__ XT, const _Float16* __restrict__ YT,
    const float* __restrict__ X, const float* __restrict__ Y,
    float* __restrict__ baryA, float* __restrict__ baryB) {
  __shared__ float gl[NN];
  __shared__ float red[4];
  __shared__ _Float16 etile[2][256 * ETW];   // 2 x 20 KB
  int id = blockIdx.x + blockIdx.y * gridDim.x + blockIdx.z * gridDim.x * gridDim.y;
  int w = (id >> 3) + (id & 7) * 64;   // 0..511, contiguous per XCD
  const int I0 = (w & 15) * 64;
  const int bz = w >> 4;               // 0..31
  const int b = bz & 15;
  const int z = bz >> 4;
  const _Float16* P = z ? A2T : A2;
  const float* rowv = z ? G : F;
  const float* colv = z ? F : G;
  const float* denom = z ? c : r;
  const _Float16* EmbT = z ? XT : YT;
  const float* Ref = z ? Y : X;
  float* baryAcc = z ? baryB : baryA;
  const int t = threadIdx.x, lane = t & 63, wave = t >> 6;
  const int m = lane & 15, quad = lane >> 4;
  gl[t] = colv[b * NN + t];
  gl[t + 256] = colv[b * NN + t + 256];
  gl[t + 512] = colv[b * NN + t + 512];
  gl[t + 768] = colv[b * NN + t + 768];
  const int row = I0 + wave * 16 + m;
  const float fi = rowv[b * NN + row] + 10.0f;        // fold 2^10 scale
  const _Float16* Pr = P + (size_t)b * NN * NN + (size_t)row * NN + quad * 8;
  const _Float16* ET = EmbT + (size_t)b * DD * NN;

  auto stageET = [&](int buf, int kc) {
#pragma unroll
    for (int i = 0; i < 4; ++i) {
      int rr = (t >> 2) + i * 64;
      int ch = t & 3;
      h8 v = *(const h8*)(ET + (size_t)rr * NN + kc + ch * 8);
      *(h8*)(&etile[buf][rr * ETW + ch * 8]) = v;
    }
  };

  f32x4 acc[16];
#pragma unroll
  for (int i = 0; i < 16; ++i) acc[i] = (f32x4){0.f, 0.f, 0.f, 0.f};
  stageET(0, 0);
  h8 a2v = *(const h8*)(Pr);                          // prime A2 pipeline
  __syncthreads();                                    // covers gl + etile[0]
  int buf = 0;
  for (int kc = 0; kc < NN; kc += 32) {
    const int kn = kc + 32;
    if (kn < NN) stageET(buf ^ 1, kn);                // prefetch next tile
    h8 a2n = a2v;
    if (kn < NN) a2n = *(const h8*)(Pr + kn);         // prefetch next a2
    float4 g0 = *(const float4*)&gl[kc + quad * 8];
    float4 g1 = *(const float4*)&gl[kc + quad * 8 + 4];
    h8 af;
    af[0] = (_Float16)EXP2F((float)a2v[0] + fi + g0.x);
    af[1] = (_Float16)EXP2F((float)a2v[1] + fi + g0.y);
    af[2] = (_Float16)EXP2F((float)a2v[2] + fi + g0.z);
    af[3] = (_Float16)EXP2F((float)a2v[3] + fi + g0.w);
    af[4] = (_Float16)EXP2F((float)a2v[4] + fi + g1.x);
    af[5] = (_Float16)EXP2F((float)a2v[5] + fi + g1.y);
    af[6] = (_Float16)EXP2F((float)a2v[6] + fi + g1.z);
    af[7] = (_Float16)EXP2F((float)a2v[7] + fi + g1.w);
#pragma unroll
    for (int nt = 0; nt < 16; ++nt) {
      h8 bf = *(const h8*)(&etile[buf][(nt * 16 + m) * ETW + quad * 8]);
      acc[nt] = __builtin_amdgcn_mfma_f32_16x16x32_f16(af, bf, acc[nt], 0, 0, 0);
    }
    a2v = a2n;
    __syncthreads();                                  // etile[buf^1] ready
    buf ^= 1;
  }
  float vs = 0.f;
#pragma unroll
  for (int r4 = 0; r4 < 4; ++r4) {
    int iabs = I0 + wave * 16 + quad * 4 + r4;
    float inv = 1.0f / (1024.0f * (denom[b * NN + iabs] + 1e-8f));
    const float* Rrow = Ref + ((size_t)b * NN + iabs) * DD;
#pragma unroll
    for (int nt = 0; nt < 16; ++nt) {
      int d = nt * 16 + m;
      float val = Rrow[d] - acc[nt][r4] * inv;
      vs = fmaf(val, val, vs);
    }
  }
  vs = waveReduceSum(vs);
  if (lane == 0) red[wave] = vs;
  __syncthreads();
  if (t == 0) atomicAdd(baryAcc + b, red[0] + red[1] + red[2] + red[3]);
}

// ---------------- K7: partial global sums X*r, Y*c ----------------
__global__ __launch_bounds__(256) void xg_kernel(
    const float* __restrict__ X, const float* __restrict__ Y,
    const float* __restrict__ r, const float* __restrict__ c,
    float* __restrict__ xgp, float* __restrict__ ygp) {
  const int b = blockIdx.y, seg = blockIdx.x, d = threadIdx.x;
  float ax = 0.f, ay = 0.f;
  for (int ii = 0; ii < 256; ++ii) {
    int i = seg * 256 + ii;
    float rvv = r[b * NN + i];
    float cvv = c[b * NN + i];
    ax = fmaf(X[((size_t)b * NN + i) * DD + d], rvv, ax);
    ay = fmaf(Y[((size_t)b * NN + i) * DD + d], cvv, ay);
  }
  xgp[(size_t)(b * 4 + seg) * DD + d] = ax;
  ygp[(size_t)(b * 4 + seg) * DD + d] = ay;
}

// ---------------- K8: per-batch finalize ----------------
__global__ __launch_bounds__(256) void finalize_batch(
    const float* __restrict__ r, const float* __restrict__ c,
    const float* __restrict__ Lrow, const float* __restrict__ xgp,
    const float* __restrict__ ygp, const float* __restrict__ baryA,
    const float* __restrict__ baryB, float* __restrict__ lossArr) {
  const int b = blockIdx.x;
  const int t = threadIdx.x;
  __shared__ float sd[256];
  auto bsum = [&](float v) -> float {
    sd[t] = v; __syncthreads();
    for (int o = 128; o; o >>= 1) { if (t < o) sd[t] += sd[t + o]; __syncthreads(); }
    float res = sd[0]; __syncthreads();
    return res;
  };
  float vr = 0.f, vc = 0.f, vl = 0.f;
  for (int k = 0; k < 4; ++k) {
    int i = t + 256 * k;
    vr += r[b * NN + i];
    vc += c[b * NN + i];
    vl += Lrow[b * NN + i];
  }
  float sumR = bsum(vr);
  float sumC = bsum(vc);
  float Lmain = bsum(vl);
  float xg = (xgp[(size_t)(b * 4 + 0) * DD + t] + xgp[(size_t)(b * 4 + 1) * DD + t] +
              xgp[(size_t)(b * 4 + 2) * DD + t] + xgp[(size_t)(b * 4 + 3) * DD + t]) /
             (sumR + 1e-8f);
  float yg = (ygp[(size_t)(b * 4 + 0) * DD + t] + ygp[(size_t)(b * 4 + 1) * DD + t] +
              ygp[(size_t)(b * 4 + 2) * DD + t] + ygp[(size_t)(b * 4 + 3) * DD + t]) /
             (sumC + 1e-8f);
  float nx = bsum(xg * xg);
  float ny = bsum(yg * yg);
  float dt = bsum(xg * yg);
  if (t == 0) {
    float mx = fmaxf(sqrtf(nx), 1e-12f);
    float my = fmaxf(sqrtf(ny), 1e-12f);
    float cosv = dt / (mx * my);
    float lb = (baryA[b] + baryB[b]) * (1.0f / ((float)NN * (float)DD));
    lossArr[b] = Lmain + 0.5f * lb + 0.2f * (1.0f - cosv);
  }
}

__global__ void final_mean(const float* __restrict__ lossArr, float* __restrict__ out) {
  int t = threadIdx.x;
  float v = (t < BB) ? lossArr[t] : 0.f;
  v = waveReduceSum(v);
  if (t == 0) out[0] = v * (1.0f / BB);
}

// ---------------- launch ----------------
extern "C" void kernel_launch(void* const* d_in, const int* in_sizes, int n_in,
                              void* d_out, int out_size, void* d_ws, size_t ws_size,
                              hipStream_t stream) {
  const float* X = (const float*)d_in[0];
  const float* Y = (const float*)d_in[1];
  float* out = (float*)d_out;
  char* ws = (char*)d_ws;
  size_t off = 0;
  auto take = [&](size_t bytes) -> char* {
    char* p = ws + off;
    off = (off + bytes + 255) & ~(size_t)255;
    return p;
  };
  _Float16* Xh = (_Float16*)take((size_t)BB * NN * DD * 2);
  _Float16* Yh = (_Float16*)take((size_t)BB * NN * DD * 2);
  _Float16* XT_h = (_Float16*)take((size_t)BB * DD * NN * 2);
  _Float16* YT_h = (_Float16*)take((size_t)BB * DD * NN * 2);
  _Float16* A2 = (_Float16*)take((size_t)BB * NN * NN * 2);
  _Float16* A2T = (_Float16*)take((size_t)BB * NN * NN * 2);
  size_t zstart = off;
  float* Cbuf = (float*)take((size_t)3 * BB * NN * 4);   // triple-buffer col sums
  float* baryA = (float*)take(64);
  float* baryB = (float*)take(64);
  unsigned* bar = (unsigned*)take((size_t)BB * 16 * 4);  // per-batch barrier counters
  size_t zlen = off - zstart;
  float* Fv = (float*)take((size_t)BB * NN * 4);
  float* Gf = (float*)take((size_t)BB * NN * 4);
  float* r = (float*)take((size_t)BB * NN * 4);
  float* c = (float*)take((size_t)BB * NN * 4);
  float* Lrow = (float*)take((size_t)BB * NN * 4);
  float* xgp = (float*)take((size_t)BB * 4 * DD * 4);
  float* ygp = (float*)take((size_t)BB * 4 * DD * 4);
  float* lossArr = (float*)take(64);
  (void)in_sizes; (void)n_in; (void)out_size; (void)ws_size;

  (void)hipMemsetAsync(ws + zstart, 0, zlen, stream);

  normalize_kernel<<<dim3(2 * BB * NN / 4), dim3(256), 0, stream>>>(X, Y, Xh, Yh);
  transpose_kernel<<<dim3(NN / 64, DD / 64, 2 * BB), dim3(256), 0, stream>>>(X, Y, XT_h,
                                                                             YT_h);
  gemm_a2_kernel<<<dim3(NN / 128, NN / 128, BB), dim3(256), 0, stream>>>(Xh, Yh, A2,
                                                                         A2T);
  // persistent sinkhorn (50 iters + final g + marginals fused), PLAIN launch:
  // 256 blocks at 1 block/CU are trivially co-resident on 256 CUs.
  (void)hipFuncSetAttribute(reinterpret_cast<const void*>(sink_persist),
                            hipFuncAttributeMaxDynamicSharedMemorySize, SINK_SMEM);
  sink_persist<<<dim3(NSLAB, BB), dim3(512), SINK_SMEM, stream>>>(A2, Cbuf, Fv, Gf, r,
                                                                  c, Lrow, bar);
  bary_mfma_kernel<<<dim3(NN / 64, BB, 2), dim3(256), 0, stream>>>(
      A2, A2T, Fv, Gf, r, c, XT_h, YT_h, X, Y, baryA, baryB);
  xg_kernel<<<dim3(4, BB), dim3(256), 0, stream>>>(X, Y, r, c, xgp, ygp);
  finalize_batch<<<dim3(BB), dim3(256), 0, stream>>>(r, c, Lrow, xgp, ygp, baryA, baryB,
                                                     lossArr);
  final_mean<<<dim3(1), dim3(64), 0, stream>>>(lossArr, out);
}